// Round 7
// baseline (264.831 us; speedup 1.0000x reference)
//
#include <hip/hip_runtime.h>
#include <stdint.h>

#define IN_C  256
#define HID   256
#define OUT_C 128
#define SCAN_BS 1024

typedef __bf16 bf16x8 __attribute__((ext_vector_type(8)));
typedef float  f32x4  __attribute__((ext_vector_type(4)));
typedef unsigned short u16x8 __attribute__((ext_vector_type(8)));
typedef unsigned short u16x4 __attribute__((ext_vector_type(4)));
typedef unsigned short u16x2 __attribute__((ext_vector_type(2)));
typedef unsigned int u32;

static __device__ __forceinline__ unsigned short f2b(float f) {
    union { float f; uint32_t u; } v; v.f = f;
    uint32_t r = v.u + 0x7fffu + ((v.u >> 16) & 1u);
    return (unsigned short)(r >> 16);
}
static __device__ __forceinline__ float b2f(unsigned short b) {
    union { uint32_t u; float f; } v; v.u = ((uint32_t)b) << 16;
    return v.f;
}
// pack 2 f32 -> u32 of 2 bf16 (RNE), 1 VALU op (proven correct in R6)
static __device__ __forceinline__ u32 cvtpk(float lo, float hi) {
    u32 r;
    asm("v_cvt_pk_bf16_f32 %0, %1, %2" : "=v"(r) : "v"(lo), "v"(hi));
    return r;
}

// ---------------- CSR build (self-loop folded in; per-edge weight precomputed) ----
__global__ void k_zero_i(int* __restrict__ p, int n) {
    int i = blockIdx.x * blockDim.x + threadIdx.x;
    if (i < n) p[i] = 0;
}

__global__ void k_count(const int* __restrict__ dst, int* __restrict__ cnt, int e) {
    int i = blockIdx.x * blockDim.x + threadIdx.x;
    if (i < e) atomicAdd(&cnt[dst[i]], 1);
}

__global__ __launch_bounds__(SCAN_BS) void k_scan_block(
    const int* __restrict__ cnt, int* __restrict__ rs, int* __restrict__ bsum, int n) {
    __shared__ int s[SCAN_BS];
    const int tid = threadIdx.x;
    const int i = blockIdx.x * SCAN_BS + tid;
    int v = (i < n) ? cnt[i] + 1 : 0;
    s[tid] = v;
    __syncthreads();
    for (int off = 1; off < SCAN_BS; off <<= 1) {
        int t = (tid >= off) ? s[tid - off] : 0;
        __syncthreads();
        s[tid] += t;
        __syncthreads();
    }
    if (i < n) rs[i] = s[tid] - v;
    if (tid == SCAN_BS - 1) bsum[blockIdx.x] = s[tid];
}

__global__ void k_scan_sums(int* __restrict__ bsum, int nb) {
    __shared__ int s[128];
    const int tid = threadIdx.x;
    int v = (tid < nb) ? bsum[tid] : 0;
    s[tid] = v;
    __syncthreads();
    for (int off = 1; off < 128; off <<= 1) {
        int t = (tid >= off) ? s[tid - off] : 0;
        __syncthreads();
        s[tid] += t;
        __syncthreads();
    }
    if (tid < nb) bsum[tid] = s[tid] - v;
}

__global__ void k_scan_add(int* __restrict__ rs, int* __restrict__ cur,
                           const int* __restrict__ bsum, const int* __restrict__ cnt,
                           float* __restrict__ dinv, int2* __restrict__ csrw, int n) {
    int i = blockIdx.x * blockDim.x + threadIdx.x;
    if (i < n) {
        int v = rs[i] + bsum[i >> 10];
        rs[i] = v;
        cur[i] = v + 1;
        float dp1 = (float)(cnt[i] + 1);
        dinv[i] = rsqrtf(dp1);
        csrw[v] = make_int2(i, __float_as_int(1.0f / dp1));   // self: weight = dinv^2
    }
}

__global__ void k_fill(const int* __restrict__ src, const int* __restrict__ dst,
                       const float* __restrict__ dinv,
                       int* __restrict__ cur, int2* __restrict__ csrw, int e) {
    int i = blockIdx.x * blockDim.x + threadIdx.x;
    if (i < e) {
        int s = src[i], d = dst[i];
        int p = atomicAdd(&cur[d], 1);
        csrw[p] = make_int2(s, __float_as_int(dinv[s] * dinv[d]));
    }
}

__global__ void k_prep(const float* __restrict__ W1, const float* __restrict__ W2,
                       unsigned short* __restrict__ W1T, unsigned short* __restrict__ W2T) {
    int i = blockIdx.x * blockDim.x + threadIdx.x;
    if (i < 65536) W1T[i] = f2b(W1[(i & 255) * HID + (i >> 8)]);
    if (i < 32768) W2T[i] = f2b(W2[(i & 255) * OUT_C + (i >> 8)]);
}

// ---------------- GEMM1: t1[n][256] bf16 = x(f32) @ W1 ----------------------
// No LDS, no barriers. 8 waves/block; wave = 64 output cols (wid&3) x row
// stream (wid>>2). B panel [64 cols][256 K] lives in registers (32 bf16x8,
// loaded once). A row-tiles (16 rows) stream from global at MFMA fragment
// layout: lane reads row (lane&15), k = kk*32 + (lane>>4)*8 -- 32B/lane/kk,
// coalesced in 128B row segments. 32 MFMA per tile, all register-resident.
__global__ __launch_bounds__(512) void k_gemm1(
    const float* __restrict__ x, const unsigned short* __restrict__ W1T,
    unsigned short* __restrict__ t1, int n, int ntiles) {
    const int tid = threadIdx.x;
    const int wid = tid >> 6, lane = tid & 63;
    const int wc0 = (wid & 3) * 64;
    const int rg  = wid >> 2;
    const int lrow = lane & 15, lgrp = lane >> 4;

    // persistent B fragments: b[nf][kk] = cols wc0+nf*16, k-slice kk
    bf16x8 b[4][8];
    #pragma unroll
    for (int nf = 0; nf < 4; ++nf)
        #pragma unroll
        for (int kk = 0; kk < 8; ++kk)
            b[nf][kk] = *(const bf16x8*)&W1T[(size_t)(wc0 + nf * 16 + lrow) * 256 + kk * 32 + lgrp * 8];

    for (int t = blockIdx.x * 2 + rg; t < ntiles; t += 512) {
        int ar = t * 16 + lrow; if (ar > n - 1) ar = n - 1;
        const float* ap = x + (size_t)ar * 256 + lgrp * 8;
        f32x4 lo[8], hi[8];
        #pragma unroll
        for (int kk = 0; kk < 8; ++kk) {
            lo[kk] = *(const f32x4*)(ap + kk * 32);
            hi[kk] = *(const f32x4*)(ap + kk * 32 + 4);
        }
        union { u32 w[4]; bf16x8 v; } a[8];
        #pragma unroll
        for (int kk = 0; kk < 8; ++kk) {
            a[kk].w[0] = cvtpk(lo[kk][0], lo[kk][1]);
            a[kk].w[1] = cvtpk(lo[kk][2], lo[kk][3]);
            a[kk].w[2] = cvtpk(hi[kk][0], hi[kk][1]);
            a[kk].w[3] = cvtpk(hi[kk][2], hi[kk][3]);
        }
        f32x4 acc[4];
        #pragma unroll
        for (int nf = 0; nf < 4; ++nf) acc[nf] = (f32x4){0.f, 0.f, 0.f, 0.f};
        #pragma unroll
        for (int kk = 0; kk < 8; ++kk)
            #pragma unroll
            for (int nf = 0; nf < 4; ++nf)
                acc[nf] = __builtin_amdgcn_mfma_f32_16x16x32_bf16(
                    a[kk].v, b[nf][kk], acc[nf], 0, 0, 0);
        unsigned short* op = t1 + ((size_t)t * 16 + lgrp * 4) * HID + wc0 + lrow;
        #pragma unroll
        for (int nf = 0; nf < 4; ++nf)
            #pragma unroll
            for (int j = 0; j < 4; ++j) {
                int r = t * 16 + lgrp * 4 + j;
                if (r < n) op[(size_t)j * HID + nf * 16] = f2b(acc[nf][j]);
            }
    }
}

// ---------------- agg1: out1 = relu(gather(t1) + b1) ------------------------
__global__ __launch_bounds__(256) void k_agg1(
    const unsigned short* __restrict__ t1, const int* __restrict__ rs,
    const int* __restrict__ cnt, const int2* __restrict__ csrw,
    const float* __restrict__ b1, unsigned short* __restrict__ out1, int n) {
    const int w = blockIdx.x * 4 + (threadIdx.x >> 6);
    const int nodeA = w * 2, nodeB = w * 2 + 1;
    if (nodeA >= n) return;
    const bool hasB = (nodeB < n);
    const int lane = threadIdx.x & 63;
    const int ch = lane * 4;
    const int begA = rs[nodeA], mA = cnt[nodeA] + 1;
    int begB = 0, mB = 0;
    if (hasB) { begB = rs[nodeB]; mB = cnt[nodeB] + 1; }
    float a0 = 0.f, a1 = 0.f, a2 = 0.f, a3 = 0.f;
    float c0 = 0.f, c1 = 0.f, c2 = 0.f, c3 = 0.f;
    const int mmax = mA > mB ? mA : mB;
    for (int j = 0; j < mmax; ++j) {
        if (j < mA) {
            int2 p = csrw[begA + j];
            float wA = __int_as_float(p.y);
            u16x4 u = *(const u16x4*)&t1[(size_t)p.x * HID + ch];
            a0 += b2f(u[0]) * wA; a1 += b2f(u[1]) * wA;
            a2 += b2f(u[2]) * wA; a3 += b2f(u[3]) * wA;
        }
        if (j < mB) {
            int2 p = csrw[begB + j];
            float wB = __int_as_float(p.y);
            u16x4 u = *(const u16x4*)&t1[(size_t)p.x * HID + ch];
            c0 += b2f(u[0]) * wB; c1 += b2f(u[1]) * wB;
            c2 += b2f(u[2]) * wB; c3 += b2f(u[3]) * wB;
        }
    }
    float4 bb = *(const float4*)(b1 + ch);
    u16x4 o;
    o[0] = f2b(fmaxf(a0 + bb.x, 0.f));
    o[1] = f2b(fmaxf(a1 + bb.y, 0.f));
    o[2] = f2b(fmaxf(a2 + bb.z, 0.f));
    o[3] = f2b(fmaxf(a3 + bb.w, 0.f));
    *(u16x4*)&out1[(size_t)nodeA * HID + ch] = o;
    if (hasB) {
        u16x4 q;
        q[0] = f2b(fmaxf(c0 + bb.x, 0.f));
        q[1] = f2b(fmaxf(c1 + bb.y, 0.f));
        q[2] = f2b(fmaxf(c2 + bb.z, 0.f));
        q[3] = f2b(fmaxf(c3 + bb.w, 0.f));
        *(u16x4*)&out1[(size_t)nodeB * HID + ch] = q;
    }
}

// ---------------- GEMM2: t2[n][128] bf16 = out1(bf16) @ W2 ------------------
// Same register-panel structure. Wave = 32 cols; B panel = 16 bf16x8 (64 VGPR).
__global__ __launch_bounds__(512) void k_gemm2(
    const unsigned short* __restrict__ out1, const unsigned short* __restrict__ W2T,
    unsigned short* __restrict__ t2, int n, int ntiles) {
    const int tid = threadIdx.x;
    const int wid = tid >> 6, lane = tid & 63;
    const int wc0 = (wid & 3) * 32;
    const int rg  = wid >> 2;
    const int lrow = lane & 15, lgrp = lane >> 4;

    bf16x8 b[2][8];
    #pragma unroll
    for (int nf = 0; nf < 2; ++nf)
        #pragma unroll
        for (int kk = 0; kk < 8; ++kk)
            b[nf][kk] = *(const bf16x8*)&W2T[(size_t)(wc0 + nf * 16 + lrow) * 256 + kk * 32 + lgrp * 8];

    for (int t = blockIdx.x * 2 + rg; t < ntiles; t += 1024) {
        int ar = t * 16 + lrow; if (ar > n - 1) ar = n - 1;
        const unsigned short* ap = out1 + (size_t)ar * HID + lgrp * 8;
        bf16x8 a[8];
        #pragma unroll
        for (int kk = 0; kk < 8; ++kk)
            a[kk] = *(const bf16x8*)(ap + kk * 32);
        f32x4 acc[2];
        acc[0] = (f32x4){0.f, 0.f, 0.f, 0.f};
        acc[1] = (f32x4){0.f, 0.f, 0.f, 0.f};
        #pragma unroll
        for (int kk = 0; kk < 8; ++kk)
            #pragma unroll
            for (int nf = 0; nf < 2; ++nf)
                acc[nf] = __builtin_amdgcn_mfma_f32_16x16x32_bf16(
                    a[kk], b[nf][kk], acc[nf], 0, 0, 0);
        unsigned short* op = t2 + ((size_t)t * 16 + lgrp * 4) * OUT_C + wc0 + lrow;
        #pragma unroll
        for (int nf = 0; nf < 2; ++nf)
            #pragma unroll
            for (int j = 0; j < 4; ++j) {
                int r = t * 16 + lgrp * 4 + j;
                if (r < n) op[(size_t)j * OUT_C + nf * 16] = f2b(acc[nf][j]);
            }
    }
}

// ---------------- agg2: out(f32) = gather(t2) + b2 --------------------------
__global__ __launch_bounds__(256) void k_agg2(
    const unsigned short* __restrict__ t2, const int* __restrict__ rs,
    const int* __restrict__ cnt, const int2* __restrict__ csrw,
    const float* __restrict__ b2, float* __restrict__ out, int n) {
    const int w = blockIdx.x * 4 + (threadIdx.x >> 6);
    const int nodeA = w * 2, nodeB = w * 2 + 1;
    if (nodeA >= n) return;
    const bool hasB = (nodeB < n);
    const int lane = threadIdx.x & 63;
    const int ch = lane * 2;
    const int begA = rs[nodeA], mA = cnt[nodeA] + 1;
    int begB = 0, mB = 0;
    if (hasB) { begB = rs[nodeB]; mB = cnt[nodeB] + 1; }
    float a0 = 0.f, a1 = 0.f, c0 = 0.f, c1 = 0.f;
    const int mmax = mA > mB ? mA : mB;
    for (int j = 0; j < mmax; ++j) {
        if (j < mA) {
            int2 p = csrw[begA + j];
            float wA = __int_as_float(p.y);
            u16x2 u = *(const u16x2*)&t2[(size_t)p.x * OUT_C + ch];
            a0 += b2f(u[0]) * wA; a1 += b2f(u[1]) * wA;
        }
        if (j < mB) {
            int2 p = csrw[begB + j];
            float wB = __int_as_float(p.y);
            u16x2 u = *(const u16x2*)&t2[(size_t)p.x * OUT_C + ch];
            c0 += b2f(u[0]) * wB; c1 += b2f(u[1]) * wB;
        }
    }
    float2 bb = *(const float2*)(b2 + ch);
    *(float2*)&out[(size_t)nodeA * OUT_C + ch] = make_float2(a0 + bb.x, a1 + bb.y);
    if (hasB)
        *(float2*)&out[(size_t)nodeB * OUT_C + ch] = make_float2(c0 + bb.x, c1 + bb.y);
}

extern "C" void kernel_launch(void* const* d_in, const int* in_sizes, int n_in,
                              void* d_out, int out_size, void* d_ws, size_t ws_size,
                              hipStream_t stream) {
    const float* x  = (const float*)d_in[0];
    const int*   ei = (const int*)d_in[1];
    const float* W1 = (const float*)d_in[2];
    const float* b1 = (const float*)d_in[3];
    const float* W2 = (const float*)d_in[4];
    const float* b2 = (const float*)d_in[5];
    float* out = (float*)d_out;

    const int n = in_sizes[0] / IN_C;   // 100000
    const int e = in_sizes[1] / 2;      // 300000
    const int* src = ei;
    const int* dst = ei + e;

    // workspace layout (4B words; csrw 8B-aligned, t1 16B-aligned)
    int*   cnt  = (int*)d_ws;                       // [n]
    int*   rs   = cnt + n;                          // [n]
    int*   cur  = rs + n;                           // [n]
    int*   bsum = cur + n;                          // [128]
    float* dinv = (float*)(bsum + 128);             // [n]
    int2*  csrw = (int2*)(dinv + n);                // [e+n] pairs {src, weight}
    unsigned short* W1T = (unsigned short*)(csrw + (size_t)e + n);  // [256*256]
    unsigned short* W2T = W1T + 65536;                              // [128*256]
    unsigned short* t1  = W2T + 32768;                              // [n*HID]
    unsigned short* out1 = t1 + (size_t)n * HID;                    // [n*HID]
    unsigned short* t2  = t1;                                       // alias

    const int nb = (n + SCAN_BS - 1) / SCAN_BS;

    k_zero_i<<<(n + 255) / 256, 256, 0, stream>>>(cnt, n);
    k_count<<<(e + 255) / 256, 256, 0, stream>>>(dst, cnt, e);
    k_scan_block<<<nb, SCAN_BS, 0, stream>>>(cnt, rs, bsum, n);
    k_scan_sums<<<1, 128, 0, stream>>>(bsum, nb);
    k_scan_add<<<(n + 255) / 256, 256, 0, stream>>>(rs, cur, bsum, cnt, dinv, csrw, n);
    k_fill<<<(e + 255) / 256, 256, 0, stream>>>(src, dst, dinv, cur, csrw, e);
    k_prep<<<256, 256, 0, stream>>>(W1, W2, W1T, W2T);

    const int ntiles = (n + 15) / 16;   // 6250
    k_gemm1<<<256, 512, 0, stream>>>(x, W1T, t1, n, ntiles);
    const int aggblk = (n + 7) / 8;
    k_agg1<<<aggblk, 256, 0, stream>>>(t1, rs, cnt, csrw, b1, out1, n);
    k_gemm2<<<512, 512, 0, stream>>>(out1, W2T, t2, n, ntiles);
    k_agg2<<<aggblk, 256, 0, stream>>>(t2, rs, cnt, csrw, b2, out, n);
}